// Round 2
// baseline (588.710 us; speedup 1.0000x reference)
//
#include <hip/hip_runtime.h>

// AdderNet forward:  x[256,1,64,64] -> adder(w1)+BN+ReLU -> adder(w2)+BN+ReLU
//                    -> avgpool -> FC -> out[256,10]
// R2: k_layer2 restructured for VALU-instruction minimality:
//  - each thread: 8-wide position span x 4 outputs (wave-uniform og quad)
//  - og quad made wave-uniform via readfirstlane -> w2 loads become s_load,
//    weights consumed as SGPR operands (zero VALU cost)
//  - 5 ds_read_b64 feed 192 math-VALU per (c,dy)  (was 2 reads per 48)
//  - pool+FC fused into one kernel

#define BATCH 256
#define HW 4096

// ---------------- Kernel 1: layer-1 stats (sum, sumsq per channel) ----------
__global__ __launch_bounds__(256) void k_stats1(const float* __restrict__ x,
                                                const float* __restrict__ w1,
                                                double* __restrict__ s1) {
  __shared__ float sx[66 * 66];
  __shared__ float red[4 * 16 * 2];
  int b = blockIdx.x, tid = threadIdx.x;
  const float* xb = x + b * HW;
  for (int i = tid; i < 66 * 66; i += 256) {
    int r = i / 66, cc = i - r * 66;
    int ry = r - 1, rx = cc - 1;
    sx[i] = (ry >= 0 && ry < 64 && rx >= 0 && rx < 64) ? xb[ry * 64 + rx] : 0.f;
  }
  __syncthreads();
  float tsum[16], tsq[16];
#pragma unroll
  for (int c = 0; c < 16; c++) { tsum[c] = 0.f; tsq[c] = 0.f; }
  for (int g = 0; g < 2; g++) {
    float wv[8][9];
#pragma unroll
    for (int c = 0; c < 8; c++)
#pragma unroll
      for (int t = 0; t < 9; t++) wv[c][t] = w1[(g * 8 + c) * 9 + t];
    for (int p = 0; p < 16; p++) {
      int pix = tid + p * 256;
      int y = pix >> 6, xx = pix & 63;
      float pa[9];
#pragma unroll
      for (int dy = 0; dy < 3; dy++)
#pragma unroll
        for (int dx = 0; dx < 3; dx++)
          pa[dy * 3 + dx] = sx[(y + dy) * 66 + xx + dx];
#pragma unroll
      for (int c = 0; c < 8; c++) {
        float acc = 0.f;
#pragma unroll
        for (int t = 0; t < 9; t++) acc += fabsf(pa[t] - wv[c][t]);
        float v = -acc;
        tsum[g * 8 + c] += v;
        tsq[g * 8 + c] += v * v;
      }
    }
  }
  int lane = tid & 63, wid = tid >> 6;
#pragma unroll
  for (int c = 0; c < 16; c++) {
    float s = tsum[c], q = tsq[c];
    for (int off = 32; off; off >>= 1) {
      s += __shfl_down(s, off, 64);
      q += __shfl_down(q, off, 64);
    }
    if (lane == 0) { red[(wid * 16 + c) * 2] = s; red[(wid * 16 + c) * 2 + 1] = q; }
  }
  __syncthreads();
  if (tid < 16) {
    float s = red[tid * 2] + red[(16 + tid) * 2] + red[(32 + tid) * 2] + red[(48 + tid) * 2];
    float q = red[tid * 2 + 1] + red[(16 + tid) * 2 + 1] + red[(32 + tid) * 2 + 1] +
              red[(48 + tid) * 2 + 1];
    atomicAdd(&s1[tid], (double)s);
    atomicAdd(&s1[16 + tid], (double)q);
  }
}

// ---------------- BN affine params ------------------------------------------
__global__ void k_bnparam(int nc, const double* __restrict__ s,
                          const float* __restrict__ g, const float* __restrict__ bt,
                          float* __restrict__ scale, float* __restrict__ shift) {
  int c = threadIdx.x;
  if (c < nc) {
    double N = 1048576.0;  // 256*64*64
    double mean = s[c] / N;
    double var = s[nc + c] / N - mean * mean;
    float inv = (float)(1.0 / sqrt(var + 1e-5));
    float sc = g[c] * inv;
    scale[c] = sc;
    shift[c] = bt[c] - (float)mean * sc;
  }
}

// ---------------- Kernel 3: layer 2 (the heavy one) -------------------------
// Block = (image b, 8-row band). Stage 1: recompute h1 tile (BN1+ReLU) in LDS.
// Stage 2: wave w handles og quads {w, w+4}; lane l: row r=l>>3, col span
// x0=8*(l&7); 8 positions x 4 outputs in registers; weights via scalar loads.
__global__ __launch_bounds__(256) void k_layer2(
    const float* __restrict__ x, const float* __restrict__ w1,
    const float* __restrict__ sc1, const float* __restrict__ sf1,
    const float* __restrict__ w2, float* __restrict__ a2,
    double* __restrict__ s2) {
  __shared__ float sxt[12 * 68];       // x tile rows y0-2..y0+9, cols -2..65
  __shared__ float sh[16 * 10 * 66];   // h1 tile [c][row y0-1..y0+8][col -1..64]
  int blk = blockIdx.x;
  int b = blk >> 3, rb = blk & 7;
  int y0 = rb * 8;
  int tid = threadIdx.x;
  const float* xb = x + b * HW;
  for (int i = tid; i < 12 * 68; i += 256) {
    int r = i / 68, cc = i - r * 68;
    int ry = y0 + r - 2, rx = cc - 2;
    sxt[i] = (ry >= 0 && ry < 64 && rx >= 0 && rx < 64) ? xb[ry * 64 + rx] : 0.f;
  }
  __syncthreads();
  // h1 recompute: same summation order as k_stats1 -> bit-identical values
  for (int c = 0; c < 16; c++) {
    float wv[9];
#pragma unroll
    for (int t = 0; t < 9; t++) wv[t] = w1[c * 9 + t];
    float sc = sc1[c], sf = sf1[c];
    for (int i = tid; i < 660; i += 256) {
      int r = i / 66, col = i - r * 66;
      int y = y0 + r - 1, xx = col - 1;
      float v = 0.f;  // h1 padding is post-activation zero
      if (y >= 0 && y < 64 && xx >= 0 && xx < 64) {
        float acc = 0.f;
#pragma unroll
        for (int dy = 0; dy < 3; dy++)
#pragma unroll
          for (int dx = 0; dx < 3; dx++)
            acc += fabsf(sxt[(r + dy) * 68 + col + dx] - wv[dy * 3 + dx]);
        v = fmaxf(fmaf(-acc, sc, sf), 0.f);
      }
      sh[c * 660 + i] = v;
    }
  }
  __syncthreads();

  int lane = tid & 63, wid = tid >> 6;
  int r = (lane >> 3);        // row within band, 0..7
  int x0 = (lane & 7) * 8;    // col span start, 0..56
  float* a2b = a2 + (size_t)b * 32 * HW;

  for (int it = 0; it < 2; it++) {
    int og = __builtin_amdgcn_readfirstlane(wid + 4 * it);  // wave-uniform quad
    float acc[4][8];
#pragma unroll
    for (int o = 0; o < 4; o++)
#pragma unroll
      for (int p = 0; p < 8; p++) acc[o][p] = 0.f;

    for (int c = 0; c < 16; c++) {
      // wave-uniform weight loads -> s_load, SGPR operands
      float wv[4][9];
#pragma unroll
      for (int o = 0; o < 4; o++) {
        const float* wp = w2 + (og * 4 + o) * 144 + c * 9;
#pragma unroll
        for (int t = 0; t < 9; t++) wv[o][t] = wp[t];
      }
#pragma unroll
      for (int dy = 0; dy < 3; dy++) {
        int base = c * 660 + (r + dy) * 66 + x0;  // even -> 8B aligned
        float a[10];
#pragma unroll
        for (int k = 0; k < 5; k++) {
          float2 q = *(const float2*)&sh[base + 2 * k];
          a[2 * k] = q.x;
          a[2 * k + 1] = q.y;
        }
#pragma unroll
        for (int o = 0; o < 4; o++) {
          float w0 = wv[o][dy * 3], w1v = wv[o][dy * 3 + 1], w2v = wv[o][dy * 3 + 2];
#pragma unroll
          for (int p = 0; p < 8; p++)
            acc[o][p] += fabsf(a[p] - w0) + fabsf(a[p + 1] - w1v) + fabsf(a[p + 2] - w2v);
        }
      }
    }
    // store + stats
    float osum[4], osq[4];
#pragma unroll
    for (int o = 0; o < 4; o++) {
      float v[8];
      float s = 0.f, q = 0.f;
#pragma unroll
      for (int p = 0; p < 8; p++) {
        v[p] = -acc[o][p];
        s += v[p];
        q += v[p] * v[p];
      }
      float* dst = a2b + (og * 4 + o) * HW + (y0 + r) * 64 + x0;
      *(float4*)dst = make_float4(v[0], v[1], v[2], v[3]);
      *(float4*)(dst + 4) = make_float4(v[4], v[5], v[6], v[7]);
      osum[o] = s;
      osq[o] = q;
    }
#pragma unroll
    for (int o = 0; o < 4; o++) {
      float s = osum[o], q = osq[o];
      for (int off = 32; off; off >>= 1) {
        s += __shfl_down(s, off, 64);
        q += __shfl_down(q, off, 64);
      }
      if (lane == 0) {
        atomicAdd(&s2[og * 4 + o], (double)s);
        atomicAdd(&s2[32 + og * 4 + o], (double)q);
      }
    }
  }
}

// ---------------- Kernel 5: BN2 + ReLU + avgpool + FC (fused) ---------------
__global__ __launch_bounds__(256) void k_poolfc(const float* __restrict__ a2,
                                                const float* __restrict__ sc2,
                                                const float* __restrict__ sf2,
                                                const float* __restrict__ fw,
                                                const float* __restrict__ fb,
                                                float* __restrict__ out) {
  int b = blockIdx.x, tid = threadIdx.x;
  int o = tid >> 3, part = tid & 7;  // 8 threads per channel
  const float* p = a2 + ((size_t)b * 32 + o) * HW;
  float s = sc2[o], f = sf2[o];
  float acc = 0.f;
  for (int i = 0; i < 128; i++) {  // 128 iters * 8 threads * 4 = 4096
    float4 v = ((const float4*)p)[i * 8 + part];
    acc += fmaxf(fmaf(v.x, s, f), 0.f) + fmaxf(fmaf(v.y, s, f), 0.f) +
           fmaxf(fmaf(v.z, s, f), 0.f) + fmaxf(fmaf(v.w, s, f), 0.f);
  }
  // reduce across the 8 threads of this channel (adjacent lanes)
  acc += __shfl_down(acc, 4, 8);
  acc += __shfl_down(acc, 2, 8);
  acc += __shfl_down(acc, 1, 8);
  __shared__ float poolv[32];
  if (part == 0) poolv[o] = acc * (1.f / 4096.f);
  __syncthreads();
  if (tid < 10) {
    float r = fb[tid];
#pragma unroll
    for (int oc = 0; oc < 32; oc++) r += poolv[oc] * fw[tid * 32 + oc];
    out[b * 10 + tid] = r;
  }
}

extern "C" void kernel_launch(void* const* d_in, const int* in_sizes, int n_in,
                              void* d_out, int out_size, void* d_ws, size_t ws_size,
                              hipStream_t stream) {
  const float* x   = (const float*)d_in[0];
  const float* w1  = (const float*)d_in[1];
  const float* g1  = (const float*)d_in[2];
  const float* b1  = (const float*)d_in[3];
  const float* w2  = (const float*)d_in[4];
  const float* g2  = (const float*)d_in[5];
  const float* b2  = (const float*)d_in[6];
  const float* fcw = (const float*)d_in[7];
  const float* fcb = (const float*)d_in[8];
  float* out = (float*)d_out;

  char* ws = (char*)d_ws;
  float* a2 = (float*)ws;                                  // 134,217,728 B
  double* stats = (double*)(ws + 134217728);               // 96 doubles
  double* s1 = stats;                                      // sum[16], sq[16]
  double* s2 = stats + 32;                                 // sum[32], sq[32]
  float* params = (float*)(ws + 134217728 + 768);
  float* sc1 = params, *sf1 = params + 16, *sc2 = params + 32, *sf2 = params + 64;

  hipMemsetAsync(stats, 0, 768, stream);
  k_stats1<<<256, 256, 0, stream>>>(x, w1, s1);
  k_bnparam<<<1, 64, 0, stream>>>(16, s1, g1, b1, sc1, sf1);
  k_layer2<<<2048, 256, 0, stream>>>(x, w1, sc1, sf1, w2, a2, s2);
  k_bnparam<<<1, 64, 0, stream>>>(32, s2, g2, b2, sc2, sf2);
  k_poolfc<<<256, 256, 0, stream>>>(a2, sc2, sf2, fcw, fcb, out);
}

// Round 3
// 464.533 us; speedup vs baseline: 1.2673x; 1.2673x over previous
//
#include <hip/hip_runtime.h>

// AdderNet forward:  x[256,1,64,64] -> adder(w1)+BN+ReLU -> adder(w2)+BN+ReLU
//                    -> avgpool -> FC -> out[256,10]
// R3: k_layer2 loop nest swapped to c-outer / og-inner with 64 register
// accumulators. Rationale (R1 post-mortem): R1 was ~41% issue-efficient;
// stalls came from per-(og,c) SMEM weight reloads (lgkmcnt(0) drains also
// flush ds_reads), 16 barriers, and 768 ds_reads/thread. c-outer gives:
//   - 6 ds_read_b64 per 1152 math VALU (8x fewer LDS reads)
//   - weight drains amortized inside a 1152-instr body
//   - 2 barriers total (stats reduced once at the end)

#define BATCH 256
#define HW 4096

// ---------------- Kernel 1: layer-1 stats (sum, sumsq per channel) ----------
__global__ __launch_bounds__(256) void k_stats1(const float* __restrict__ x,
                                                const float* __restrict__ w1,
                                                double* __restrict__ s1) {
  __shared__ float sx[66 * 66];
  __shared__ float red[4 * 16 * 2];
  int b = blockIdx.x, tid = threadIdx.x;
  const float* xb = x + b * HW;
  for (int i = tid; i < 66 * 66; i += 256) {
    int r = i / 66, cc = i - r * 66;
    int ry = r - 1, rx = cc - 1;
    sx[i] = (ry >= 0 && ry < 64 && rx >= 0 && rx < 64) ? xb[ry * 64 + rx] : 0.f;
  }
  __syncthreads();
  float tsum[16], tsq[16];
#pragma unroll
  for (int c = 0; c < 16; c++) { tsum[c] = 0.f; tsq[c] = 0.f; }
  for (int g = 0; g < 2; g++) {
    float wv[8][9];
#pragma unroll
    for (int c = 0; c < 8; c++)
#pragma unroll
      for (int t = 0; t < 9; t++) wv[c][t] = w1[(g * 8 + c) * 9 + t];
    for (int p = 0; p < 16; p++) {
      int pix = tid + p * 256;
      int y = pix >> 6, xx = pix & 63;
      float pa[9];
#pragma unroll
      for (int dy = 0; dy < 3; dy++)
#pragma unroll
        for (int dx = 0; dx < 3; dx++)
          pa[dy * 3 + dx] = sx[(y + dy) * 66 + xx + dx];
#pragma unroll
      for (int c = 0; c < 8; c++) {
        float acc = 0.f;
#pragma unroll
        for (int t = 0; t < 9; t++) acc += fabsf(pa[t] - wv[c][t]);
        float v = -acc;
        tsum[g * 8 + c] += v;
        tsq[g * 8 + c] += v * v;
      }
    }
  }
  int lane = tid & 63, wid = tid >> 6;
#pragma unroll
  for (int c = 0; c < 16; c++) {
    float s = tsum[c], q = tsq[c];
    for (int off = 32; off; off >>= 1) {
      s += __shfl_down(s, off, 64);
      q += __shfl_down(q, off, 64);
    }
    if (lane == 0) { red[(wid * 16 + c) * 2] = s; red[(wid * 16 + c) * 2 + 1] = q; }
  }
  __syncthreads();
  if (tid < 16) {
    float s = red[tid * 2] + red[(16 + tid) * 2] + red[(32 + tid) * 2] + red[(48 + tid) * 2];
    float q = red[tid * 2 + 1] + red[(16 + tid) * 2 + 1] + red[(32 + tid) * 2 + 1] +
              red[(48 + tid) * 2 + 1];
    atomicAdd(&s1[tid], (double)s);
    atomicAdd(&s1[16 + tid], (double)q);
  }
}

// ---------------- BN affine params ------------------------------------------
__global__ void k_bnparam(int nc, const double* __restrict__ s,
                          const float* __restrict__ g, const float* __restrict__ bt,
                          float* __restrict__ scale, float* __restrict__ shift) {
  int c = threadIdx.x;
  if (c < nc) {
    double N = 1048576.0;  // 256*64*64
    double mean = s[c] / N;
    double var = s[nc + c] / N - mean * mean;
    float inv = (float)(1.0 / sqrt(var + 1e-5));
    float sc = g[c] * inv;
    scale[c] = sc;
    shift[c] = bt[c] - (float)mean * sc;
  }
}

// ---------------- Kernel 3: layer 2 (the heavy one) -------------------------
// Block = (image b, 8-row band). Stage 1: recompute h1 tile (BN1+ReLU) in LDS.
// Stage 2: c-outer loop; per c, load 3x4 activation window once, then fully
// unrolled og(8) x o(4) x dy(3) math into acc[8][4][2] (64 VGPR accumulators).
__global__ __launch_bounds__(256, 3) void k_layer2(
    const float* __restrict__ x, const float* __restrict__ w1,
    const float* __restrict__ sc1, const float* __restrict__ sf1,
    const float* __restrict__ w2, float* __restrict__ a2,
    double* __restrict__ s2) {
  __shared__ float sxt[12 * 68];       // x tile rows y0-2..y0+9, cols -2..65
  __shared__ float sh[16 * 660];       // h1 tile [c][row y0-1..y0+8][col -1..64]
  __shared__ float red[4 * 64];        // per-wave stats partials
  int blk = blockIdx.x;
  int b = blk >> 3, rb = blk & 7;
  int y0 = rb * 8;
  int tid = threadIdx.x;
  const float* xb = x + b * HW;
  for (int i = tid; i < 12 * 68; i += 256) {
    int r = i / 68, cc = i - r * 68;
    int ry = y0 + r - 2, rx = cc - 2;
    sxt[i] = (ry >= 0 && ry < 64 && rx >= 0 && rx < 64) ? xb[ry * 64 + rx] : 0.f;
  }
  __syncthreads();
  // h1 recompute: same summation order as k_stats1 -> bit-identical values
  for (int c = 0; c < 16; c++) {
    float wv[9];
#pragma unroll
    for (int t = 0; t < 9; t++) wv[t] = w1[c * 9 + t];
    float sc = sc1[c], sf = sf1[c];
    for (int i = tid; i < 660; i += 256) {
      int r = i / 66, col = i - r * 66;
      int y = y0 + r - 1, xx = col - 1;
      float v = 0.f;  // h1 padding is post-activation zero
      if (y >= 0 && y < 64 && xx >= 0 && xx < 64) {
        float acc = 0.f;
#pragma unroll
        for (int dy = 0; dy < 3; dy++)
#pragma unroll
          for (int dx = 0; dx < 3; dx++)
            acc += fabsf(sxt[(r + dy) * 68 + col + dx] - wv[dy * 3 + dx]);
        v = fmaxf(fmaf(-acc, sc, sf), 0.f);
      }
      sh[c * 660 + i] = v;
    }
  }
  __syncthreads();

  int lane = tid & 63, wid = tid >> 6;
  int r = tid >> 5;           // row within band, 0..7
  int x0 = (tid & 31) * 2;    // col span start (even -> 8B-aligned LDS reads)

  float acc[8][4][2];
#pragma unroll
  for (int og = 0; og < 8; og++)
#pragma unroll
    for (int o = 0; o < 4; o++) { acc[og][o][0] = 0.f; acc[og][o][1] = 0.f; }

  for (int c = 0; c < 16; c++) {
    float a[3][4];
#pragma unroll
    for (int dy = 0; dy < 3; dy++) {
      const float* rp = &sh[c * 660 + (r + dy) * 66 + x0];
      float2 q0 = *(const float2*)rp;
      float2 q1 = *(const float2*)(rp + 2);
      a[dy][0] = q0.x; a[dy][1] = q0.y; a[dy][2] = q1.x; a[dy][3] = q1.y;
    }
    const float* wc = w2 + c * 9;  // uniform -> scalar loads
#pragma unroll
    for (int og = 0; og < 8; og++)
#pragma unroll
      for (int o = 0; o < 4; o++) {
        const float* wp = wc + (og * 4 + o) * 144;
#pragma unroll
        for (int dy = 0; dy < 3; dy++) {
          float w0 = wp[dy * 3], w1v = wp[dy * 3 + 1], w2v = wp[dy * 3 + 2];
          acc[og][o][0] +=
              fabsf(a[dy][0] - w0) + fabsf(a[dy][1] - w1v) + fabsf(a[dy][2] - w2v);
          acc[og][o][1] +=
              fabsf(a[dy][1] - w0) + fabsf(a[dy][2] - w1v) + fabsf(a[dy][3] - w2v);
        }
      }
  }

  // store a2 + per-wave stats partials
  float* a2b = a2 + (size_t)b * 32 * HW + (y0 + r) * 64 + x0;
#pragma unroll
  for (int og = 0; og < 8; og++)
#pragma unroll
    for (int o = 0; o < 4; o++) {
      float v0 = -acc[og][o][0], v1 = -acc[og][o][1];
      *(float2*)(a2b + (og * 4 + o) * HW) = make_float2(v0, v1);
      float s = v0 + v1, q = v0 * v0 + v1 * v1;
      for (int off = 32; off; off >>= 1) {
        s += __shfl_down(s, off, 64);
        q += __shfl_down(q, off, 64);
      }
      if (lane == 0) {
        red[wid * 64 + (og * 4 + o) * 2] = s;
        red[wid * 64 + (og * 4 + o) * 2 + 1] = q;
      }
    }
  __syncthreads();
  if (tid < 32) {
    float s = red[tid * 2] + red[64 + tid * 2] + red[128 + tid * 2] + red[192 + tid * 2];
    float q = red[tid * 2 + 1] + red[64 + tid * 2 + 1] + red[128 + tid * 2 + 1] +
              red[192 + tid * 2 + 1];
    atomicAdd(&s2[tid], (double)s);
    atomicAdd(&s2[32 + tid], (double)q);
  }
}

// ---------------- Kernel 5: BN2 + ReLU + avgpool + FC (fused) ---------------
// 1024 threads/block (16 waves/CU at 1 block/CU) for memory-latency hiding.
__global__ __launch_bounds__(1024) void k_poolfc(const float* __restrict__ a2,
                                                 const float* __restrict__ sc2,
                                                 const float* __restrict__ sf2,
                                                 const float* __restrict__ fw,
                                                 const float* __restrict__ fb,
                                                 float* __restrict__ out) {
  int b = blockIdx.x, tid = threadIdx.x;
  int o = tid >> 5, part = tid & 31;  // 32 threads per channel
  const float4* p = (const float4*)(a2 + ((size_t)b * 32 + o) * HW);
  float s = sc2[o], f = sf2[o];
  float acc = 0.f;
#pragma unroll
  for (int i = 0; i < 32; i++) {  // 32 iters * 32 threads * 4 = 4096
    float4 v = p[i * 32 + part];
    acc += fmaxf(fmaf(v.x, s, f), 0.f) + fmaxf(fmaf(v.y, s, f), 0.f) +
           fmaxf(fmaf(v.z, s, f), 0.f) + fmaxf(fmaf(v.w, s, f), 0.f);
  }
  acc += __shfl_down(acc, 16, 32);
  acc += __shfl_down(acc, 8, 32);
  acc += __shfl_down(acc, 4, 32);
  acc += __shfl_down(acc, 2, 32);
  acc += __shfl_down(acc, 1, 32);
  __shared__ float poolv[32];
  if (part == 0) poolv[o] = acc * (1.f / 4096.f);
  __syncthreads();
  if (tid < 10) {
    float rr = fb[tid];
#pragma unroll
    for (int oc = 0; oc < 32; oc++) rr += poolv[oc] * fw[tid * 32 + oc];
    out[b * 10 + tid] = rr;
  }
}

extern "C" void kernel_launch(void* const* d_in, const int* in_sizes, int n_in,
                              void* d_out, int out_size, void* d_ws, size_t ws_size,
                              hipStream_t stream) {
  const float* x   = (const float*)d_in[0];
  const float* w1  = (const float*)d_in[1];
  const float* g1  = (const float*)d_in[2];
  const float* b1  = (const float*)d_in[3];
  const float* w2  = (const float*)d_in[4];
  const float* g2  = (const float*)d_in[5];
  const float* b2  = (const float*)d_in[6];
  const float* fcw = (const float*)d_in[7];
  const float* fcb = (const float*)d_in[8];
  float* out = (float*)d_out;

  char* ws = (char*)d_ws;
  float* a2 = (float*)ws;                                  // 134,217,728 B
  double* stats = (double*)(ws + 134217728);               // 96 doubles
  double* s1 = stats;                                      // sum[16], sq[16]
  double* s2 = stats + 32;                                 // sum[32], sq[32]
  float* params = (float*)(ws + 134217728 + 768);
  float* sc1 = params, *sf1 = params + 16, *sc2 = params + 32, *sf2 = params + 64;

  hipMemsetAsync(stats, 0, 768, stream);
  k_stats1<<<256, 256, 0, stream>>>(x, w1, s1);
  k_bnparam<<<1, 64, 0, stream>>>(16, s1, g1, b1, sc1, sf1);
  k_layer2<<<2048, 256, 0, stream>>>(x, w1, sc1, sf1, w2, a2, s2);
  k_bnparam<<<1, 64, 0, stream>>>(32, s2, g2, b2, sc2, sf2);
  k_poolfc<<<256, 1024, 0, stream>>>(a2, sc2, sf2, fcw, fcb, out);
}

// Round 4
// 431.776 us; speedup vs baseline: 1.3635x; 1.0759x over previous
//
#include <hip/hip_runtime.h>

// AdderNet forward:  x[256,1,64,64] -> adder(w1)+BN+ReLU -> adder(w2)+BN+ReLU
//                    -> avgpool -> FC -> out[256,10]
// R4: o-block=8 (4 og-passes) so live state fits register files:
//   acc[8][2]=16 VGPRs (R3's 64 accs spilled to AGPRs -> 2.7x VALU inflation),
//   72 weight floats/pass -> SGPRs via s_load (uniform addresses).
//   Per c-iter: 6 ds_read_b64 (offset-immediate) feed 288 math VALU.
//   #pragma unroll 1 on og/c loops keeps body ~3KB (icache).
//   bnparam kernels folded inline (block-redundant) -> 4 launches total.

#define BATCH 256
#define HW 4096

// ---------------- Kernel 1: layer-1 stats (sum, sumsq per channel) ----------
__global__ __launch_bounds__(256) void k_stats1(const float* __restrict__ x,
                                                const float* __restrict__ w1,
                                                double* __restrict__ s1) {
  __shared__ float sx[66 * 66];
  __shared__ float red[4 * 16 * 2];
  int b = blockIdx.x, tid = threadIdx.x;
  const float* xb = x + b * HW;
  for (int i = tid; i < 66 * 66; i += 256) {
    int r = i / 66, cc = i - r * 66;
    int ry = r - 1, rx = cc - 1;
    sx[i] = (ry >= 0 && ry < 64 && rx >= 0 && rx < 64) ? xb[ry * 64 + rx] : 0.f;
  }
  __syncthreads();
  float tsum[16], tsq[16];
#pragma unroll
  for (int c = 0; c < 16; c++) { tsum[c] = 0.f; tsq[c] = 0.f; }
  for (int g = 0; g < 2; g++) {
    float wv[8][9];
#pragma unroll
    for (int c = 0; c < 8; c++)
#pragma unroll
      for (int t = 0; t < 9; t++) wv[c][t] = w1[(g * 8 + c) * 9 + t];
    for (int p = 0; p < 16; p++) {
      int pix = tid + p * 256;
      int y = pix >> 6, xx = pix & 63;
      float pa[9];
#pragma unroll
      for (int dy = 0; dy < 3; dy++)
#pragma unroll
        for (int dx = 0; dx < 3; dx++)
          pa[dy * 3 + dx] = sx[(y + dy) * 66 + xx + dx];
#pragma unroll
      for (int c = 0; c < 8; c++) {
        float acc = 0.f;
#pragma unroll
        for (int t = 0; t < 9; t++) acc += fabsf(pa[t] - wv[c][t]);
        float v = -acc;
        tsum[g * 8 + c] += v;
        tsq[g * 8 + c] += v * v;
      }
    }
  }
  int lane = tid & 63, wid = tid >> 6;
#pragma unroll
  for (int c = 0; c < 16; c++) {
    float s = tsum[c], q = tsq[c];
    for (int off = 32; off; off >>= 1) {
      s += __shfl_down(s, off, 64);
      q += __shfl_down(q, off, 64);
    }
    if (lane == 0) { red[(wid * 16 + c) * 2] = s; red[(wid * 16 + c) * 2 + 1] = q; }
  }
  __syncthreads();
  if (tid < 16) {
    float s = red[tid * 2] + red[(16 + tid) * 2] + red[(32 + tid) * 2] + red[(48 + tid) * 2];
    float q = red[tid * 2 + 1] + red[(16 + tid) * 2 + 1] + red[(32 + tid) * 2 + 1] +
              red[(48 + tid) * 2 + 1];
    atomicAdd(&s1[tid], (double)s);
    atomicAdd(&s1[16 + tid], (double)q);
  }
}

// ---------------- Kernel 2: layer 2 (the heavy one) -------------------------
// Block = (image b, 8-row band). Stage 0: inline BN1 params from fp64 stats.
// Stage 1: recompute h1 tile (BN1+ReLU) into LDS (bit-identical to k_stats1).
// Stage 2: 4 og-passes; per pass 8 outputs x 2 positions in 16 VGPR accs;
// weights via uniform s_load; LDS reads use offset immediates.
__global__ __launch_bounds__(256, 3) void k_layer2(
    const float* __restrict__ x, const float* __restrict__ w1,
    const double* __restrict__ s1, const float* __restrict__ g1,
    const float* __restrict__ b1, const float* __restrict__ w2,
    float* __restrict__ a2, double* __restrict__ s2) {
  __shared__ float sxt[12 * 68];       // x tile rows y0-2..y0+9, cols -2..65
  __shared__ float sh[16 * 660];       // h1 tile [c][row y0-1..y0+8][col -1..64]
  __shared__ float red[4 * 64];        // per-wave stats partials
  __shared__ float sc1s[16], sf1s[16];
  int blk = blockIdx.x;
  int b = blk >> 3, rb = blk & 7;
  int y0 = rb * 8;
  int tid = threadIdx.x;

  if (tid < 16) {  // inline BN1 params (block-redundant)
    double N = 1048576.0;
    double mean = s1[tid] / N;
    double var = s1[16 + tid] / N - mean * mean;
    float inv = (float)(1.0 / sqrt(var + 1e-5));
    float sc = g1[tid] * inv;
    sc1s[tid] = sc;
    sf1s[tid] = b1[tid] - (float)mean * sc;
  }
  const float* xb = x + b * HW;
  for (int i = tid; i < 12 * 68; i += 256) {
    int r = i / 68, cc = i - r * 68;
    int ry = y0 + r - 2, rx = cc - 2;
    sxt[i] = (ry >= 0 && ry < 64 && rx >= 0 && rx < 64) ? xb[ry * 64 + rx] : 0.f;
  }
  __syncthreads();
  // h1 recompute: same summation order as k_stats1 -> bit-identical values
  for (int c = 0; c < 16; c++) {
    float wv[9];
#pragma unroll
    for (int t = 0; t < 9; t++) wv[t] = w1[c * 9 + t];
    float sc = sc1s[c], sf = sf1s[c];
    for (int i = tid; i < 660; i += 256) {
      int r = i / 66, col = i - r * 66;
      int y = y0 + r - 1, xx = col - 1;
      float v = 0.f;  // h1 padding is post-activation zero
      if (y >= 0 && y < 64 && xx >= 0 && xx < 64) {
        float acc = 0.f;
#pragma unroll
        for (int dy = 0; dy < 3; dy++)
#pragma unroll
          for (int dx = 0; dx < 3; dx++)
            acc += fabsf(sxt[(r + dy) * 68 + col + dx] - wv[dy * 3 + dx]);
        v = fmaxf(fmaf(-acc, sc, sf), 0.f);
      }
      sh[c * 660 + i] = v;
    }
  }
  __syncthreads();

  int lane = tid & 63, wid = tid >> 6;
  int r = tid >> 5;           // row within band, 0..7
  int x0 = (tid & 31) * 2;    // col span start (even -> 8B-aligned LDS reads)
  const float* shbase = &sh[r * 66 + x0];
  float* a2b = a2 + (size_t)b * 32 * HW + (y0 + r) * 64 + x0;

#pragma unroll 1
  for (int og = 0; og < 4; og++) {
    float acc[8][2];
#pragma unroll
    for (int o = 0; o < 8; o++) { acc[o][0] = 0.f; acc[o][1] = 0.f; }

#pragma unroll 1
    for (int c = 0; c < 16; c++) {
      float a[3][4];
#pragma unroll
      for (int dy = 0; dy < 3; dy++) {
        const float* rp = shbase + c * 660 + dy * 66;
        float2 q0 = *(const float2*)rp;
        float2 q1 = *(const float2*)(rp + 2);
        a[dy][0] = q0.x; a[dy][1] = q0.y; a[dy][2] = q1.x; a[dy][3] = q1.y;
      }
      const float* wc = w2 + (og * 8) * 144 + c * 9;  // uniform -> s_load
#pragma unroll
      for (int o = 0; o < 8; o++) {
        const float* wp = wc + o * 144;
#pragma unroll
        for (int dy = 0; dy < 3; dy++) {
          float w0 = wp[dy * 3], w1v = wp[dy * 3 + 1], w2v = wp[dy * 3 + 2];
          acc[o][0] += fabsf(a[dy][0] - w0) + fabsf(a[dy][1] - w1v) + fabsf(a[dy][2] - w2v);
          acc[o][1] += fabsf(a[dy][1] - w0) + fabsf(a[dy][2] - w1v) + fabsf(a[dy][3] - w2v);
        }
      }
    }
    // store + per-wave stats partials
#pragma unroll
    for (int o = 0; o < 8; o++) {
      float v0 = -acc[o][0], v1 = -acc[o][1];
      *(float2*)(a2b + (og * 8 + o) * HW) = make_float2(v0, v1);
      float s = v0 + v1, q = v0 * v0 + v1 * v1;
      for (int off = 32; off; off >>= 1) {
        s += __shfl_down(s, off, 64);
        q += __shfl_down(q, off, 64);
      }
      if (lane == 0) {
        red[wid * 64 + (og * 8 + o) * 2] = s;
        red[wid * 64 + (og * 8 + o) * 2 + 1] = q;
      }
    }
  }
  __syncthreads();
  if (tid < 32) {
    float s = red[tid * 2] + red[64 + tid * 2] + red[128 + tid * 2] + red[192 + tid * 2];
    float q = red[tid * 2 + 1] + red[64 + tid * 2 + 1] + red[128 + tid * 2 + 1] +
              red[192 + tid * 2 + 1];
    atomicAdd(&s2[tid], (double)s);
    atomicAdd(&s2[32 + tid], (double)q);
  }
}

// ---------------- Kernel 3: BN2 (inline params) + ReLU + avgpool + FC -------
__global__ __launch_bounds__(1024) void k_poolfc(const float* __restrict__ a2,
                                                 const double* __restrict__ s2,
                                                 const float* __restrict__ g2,
                                                 const float* __restrict__ b2,
                                                 const float* __restrict__ fw,
                                                 const float* __restrict__ fb,
                                                 float* __restrict__ out) {
  __shared__ float sc2s[32], sf2s[32];
  __shared__ float poolv[32];
  int b = blockIdx.x, tid = threadIdx.x;
  if (tid < 32) {  // inline BN2 params (block-redundant)
    double N = 1048576.0;
    double mean = s2[tid] / N;
    double var = s2[32 + tid] / N - mean * mean;
    float inv = (float)(1.0 / sqrt(var + 1e-5));
    float sc = g2[tid] * inv;
    sc2s[tid] = sc;
    sf2s[tid] = b2[tid] - (float)mean * sc;
  }
  __syncthreads();
  int o = tid >> 5, part = tid & 31;  // 32 threads per channel
  const float4* p = (const float4*)(a2 + ((size_t)b * 32 + o) * HW);
  float s = sc2s[o], f = sf2s[o];
  float acc = 0.f;
#pragma unroll
  for (int i = 0; i < 32; i++) {  // 32 iters * 32 threads * 4 = 4096
    float4 v = p[i * 32 + part];
    acc += fmaxf(fmaf(v.x, s, f), 0.f) + fmaxf(fmaf(v.y, s, f), 0.f) +
           fmaxf(fmaf(v.z, s, f), 0.f) + fmaxf(fmaf(v.w, s, f), 0.f);
  }
  acc += __shfl_down(acc, 16, 32);
  acc += __shfl_down(acc, 8, 32);
  acc += __shfl_down(acc, 4, 32);
  acc += __shfl_down(acc, 2, 32);
  acc += __shfl_down(acc, 1, 32);
  if (part == 0) poolv[o] = acc * (1.f / 4096.f);
  __syncthreads();
  if (tid < 10) {
    float rr = fb[tid];
#pragma unroll
    for (int oc = 0; oc < 32; oc++) rr += poolv[oc] * fw[tid * 32 + oc];
    out[b * 10 + tid] = rr;
  }
}

extern "C" void kernel_launch(void* const* d_in, const int* in_sizes, int n_in,
                              void* d_out, int out_size, void* d_ws, size_t ws_size,
                              hipStream_t stream) {
  const float* x   = (const float*)d_in[0];
  const float* w1  = (const float*)d_in[1];
  const float* g1  = (const float*)d_in[2];
  const float* b1  = (const float*)d_in[3];
  const float* w2  = (const float*)d_in[4];
  const float* g2  = (const float*)d_in[5];
  const float* b2  = (const float*)d_in[6];
  const float* fcw = (const float*)d_in[7];
  const float* fcb = (const float*)d_in[8];
  float* out = (float*)d_out;

  char* ws = (char*)d_ws;
  float* a2 = (float*)ws;                                  // 134,217,728 B
  double* stats = (double*)(ws + 134217728);               // 96 doubles
  double* s1 = stats;                                      // sum[16], sq[16]
  double* s2 = stats + 32;                                 // sum[32], sq[32]

  hipMemsetAsync(stats, 0, 768, stream);
  k_stats1<<<256, 256, 0, stream>>>(x, w1, s1);
  k_layer2<<<2048, 256, 0, stream>>>(x, w1, s1, g1, b1, w2, a2, s2);
  k_poolfc<<<256, 1024, 0, stream>>>(a2, s2, g2, b2, fcw, fcb, out);
}

// Round 5
// 413.615 us; speedup vs baseline: 1.4233x; 1.0439x over previous
//
#include <hip/hip_runtime.h>

// AdderNet forward:  x[256,1,64,64] -> adder(w1)+BN+ReLU -> adder(w2)+BN+ReLU
//                    -> avgpool -> FC -> out[256,10]
// R5: occupancy + latency-hiding attack on k_layer2.
//   - 4-row bands (4096 blocks): LDS 46->28KB => 5 blocks/CU (20 waves vs 12)
//   - og-space split across wave pairs (readfirstlane keeps weights scalar)
//   - activation LDS reads register-double-buffered (prefetch c+1 before
//     math of c) so per-iteration lgkmcnt waits find completed loads
//   - R1/R3/R4 all ~360-390us despite different inner loops => bottleneck is
//     correlated stalls at 3 waves/SIMD, not instruction count (true VALU
//     busy ~40%; derived 88% is gfx94x-formula inflated)

#define BATCH 256
#define HW 4096

// ---------------- Kernel 1: layer-1 stats (sum, sumsq per channel) ----------
__global__ __launch_bounds__(256) void k_stats1(const float* __restrict__ x,
                                                const float* __restrict__ w1,
                                                double* __restrict__ s1) {
  __shared__ float sx[66 * 66];
  __shared__ float red[4 * 16 * 2];
  int b = blockIdx.x, tid = threadIdx.x;
  const float* xb = x + b * HW;
  for (int i = tid; i < 66 * 66; i += 256) {
    int r = i / 66, cc = i - r * 66;
    int ry = r - 1, rx = cc - 1;
    sx[i] = (ry >= 0 && ry < 64 && rx >= 0 && rx < 64) ? xb[ry * 64 + rx] : 0.f;
  }
  __syncthreads();
  float tsum[16], tsq[16];
#pragma unroll
  for (int c = 0; c < 16; c++) { tsum[c] = 0.f; tsq[c] = 0.f; }
  for (int g = 0; g < 2; g++) {
    float wv[8][9];
#pragma unroll
    for (int c = 0; c < 8; c++)
#pragma unroll
      for (int t = 0; t < 9; t++) wv[c][t] = w1[(g * 8 + c) * 9 + t];
    for (int p = 0; p < 16; p++) {
      int pix = tid + p * 256;
      int y = pix >> 6, xx = pix & 63;
      float pa[9];
#pragma unroll
      for (int dy = 0; dy < 3; dy++)
#pragma unroll
        for (int dx = 0; dx < 3; dx++)
          pa[dy * 3 + dx] = sx[(y + dy) * 66 + xx + dx];
#pragma unroll
      for (int c = 0; c < 8; c++) {
        float acc = 0.f;
#pragma unroll
        for (int t = 0; t < 9; t++) acc += fabsf(pa[t] - wv[c][t]);
        float v = -acc;
        tsum[g * 8 + c] += v;
        tsq[g * 8 + c] += v * v;
      }
    }
  }
  int lane = tid & 63, wid = tid >> 6;
#pragma unroll
  for (int c = 0; c < 16; c++) {
    float s = tsum[c], q = tsq[c];
    for (int off = 32; off; off >>= 1) {
      s += __shfl_down(s, off, 64);
      q += __shfl_down(q, off, 64);
    }
    if (lane == 0) { red[(wid * 16 + c) * 2] = s; red[(wid * 16 + c) * 2 + 1] = q; }
  }
  __syncthreads();
  if (tid < 16) {
    float s = red[tid * 2] + red[(16 + tid) * 2] + red[(32 + tid) * 2] + red[(48 + tid) * 2];
    float q = red[tid * 2 + 1] + red[(16 + tid) * 2 + 1] + red[(32 + tid) * 2 + 1] +
              red[(48 + tid) * 2 + 1];
    atomicAdd(&s1[tid], (double)s);
    atomicAdd(&s1[16 + tid], (double)q);
  }
}

// ---------------- Kernel 2: layer 2 (the heavy one) -------------------------
// Block = (image b, 4-row band). Stage 0: inline BN1 params. Stage 1: h1 tile
// (rows y0-1..y0+4) into LDS. Stage 2: wave-pair og split; 2 og-passes of
// 8 outputs x 2 positions; activation reads double-buffered in registers.
__global__ __launch_bounds__(256, 5) void k_layer2(
    const float* __restrict__ x, const float* __restrict__ w1,
    const double* __restrict__ s1, const float* __restrict__ g1,
    const float* __restrict__ b1, const float* __restrict__ w2,
    float* __restrict__ a2, double* __restrict__ s2) {
  __shared__ float sxt[8 * 68];        // x rows y0-2..y0+5, cols -2..65
  __shared__ float sh[16 * 6 * 66];    // h1 [c][row y0-1..y0+4][col -1..64]
  __shared__ float red[4 * 32];        // per-wave stats partials (s,q)
  __shared__ float sc1s[16], sf1s[16];
  int blk = blockIdx.x;
  int b = blk >> 4, rb = blk & 15;
  int y0 = rb * 4;
  int tid = threadIdx.x;

  if (tid < 16) {  // inline BN1 params (block-redundant)
    double N = 1048576.0;
    double mean = s1[tid] / N;
    double var = s1[16 + tid] / N - mean * mean;
    float inv = (float)(1.0 / sqrt(var + 1e-5));
    float sc = g1[tid] * inv;
    sc1s[tid] = sc;
    sf1s[tid] = b1[tid] - (float)mean * sc;
  }
  const float* xb = x + b * HW;
  for (int i = tid; i < 8 * 68; i += 256) {
    int r = i / 68, cc = i - r * 68;
    int ry = y0 + r - 2, rx = cc - 2;
    sxt[i] = (ry >= 0 && ry < 64 && rx >= 0 && rx < 64) ? xb[ry * 64 + rx] : 0.f;
  }
  __syncthreads();
  // h1 recompute (same summation order as k_stats1)
  for (int c = 0; c < 16; c++) {
    float wv[9];
#pragma unroll
    for (int t = 0; t < 9; t++) wv[t] = w1[c * 9 + t];
    float sc = sc1s[c], sf = sf1s[c];
    for (int i = tid; i < 396; i += 256) {
      int r = i / 66, col = i - r * 66;
      int y = y0 + r - 1, xx = col - 1;
      float v = 0.f;  // h1 padding is post-activation zero
      if (y >= 0 && y < 64 && xx >= 0 && xx < 64) {
        float acc = 0.f;
#pragma unroll
        for (int dy = 0; dy < 3; dy++)
#pragma unroll
          for (int dx = 0; dx < 3; dx++)
            acc += fabsf(sxt[(r + dy) * 68 + col + dx] - wv[dy * 3 + dx]);
        v = fmaxf(fmaf(-acc, sc, sf), 0.f);
      }
      sh[c * 396 + i] = v;
    }
  }
  __syncthreads();

  int lane = tid & 63, wid = tid >> 6;
  int r = (tid >> 5) & 3;     // row within band, 0..3
  int x0 = (tid & 31) * 2;    // col span start (8B-aligned LDS reads)
  int oh = __builtin_amdgcn_readfirstlane(tid >> 7);  // og half, wave-uniform
  const float* shbase = &sh[r * 66 + x0];
  float* a2b = a2 + (size_t)b * 32 * HW + (y0 + r) * 64 + x0;

#pragma unroll 1
  for (int p = 0; p < 2; p++) {
    int ogb = (oh * 2 + p) * 8;  // base output channel of this pass
    float acc[8][2];
#pragma unroll
    for (int o = 0; o < 8; o++) { acc[o][0] = 0.f; acc[o][1] = 0.f; }

    // prefetch activations for c=0
    float2 nx[6];
#pragma unroll
    for (int dy = 0; dy < 3; dy++) {
      const float* rp = shbase + dy * 66;
      nx[dy * 2] = *(const float2*)rp;
      nx[dy * 2 + 1] = *(const float2*)(rp + 2);
    }

#pragma unroll 1
    for (int c = 0; c < 16; c++) {
      float2 cu[6];
#pragma unroll
      for (int j = 0; j < 6; j++) cu[j] = nx[j];
      if (c < 15) {  // issue next-iteration loads before math
        const float* nb = shbase + (c + 1) * 396;
#pragma unroll
        for (int dy = 0; dy < 3; dy++) {
          const float* rp = nb + dy * 66;
          nx[dy * 2] = *(const float2*)rp;
          nx[dy * 2 + 1] = *(const float2*)(rp + 2);
        }
      }
      const float* wc = w2 + ogb * 144 + c * 9;  // uniform -> s_load
#pragma unroll
      for (int o = 0; o < 8; o++) {
        const float* wp = wc + o * 144;
#pragma unroll
        for (int dy = 0; dy < 3; dy++) {
          float w0 = wp[dy * 3], w1v = wp[dy * 3 + 1], w2v = wp[dy * 3 + 2];
          float a0 = cu[dy * 2].x, a1 = cu[dy * 2].y;
          float a2v = cu[dy * 2 + 1].x, a3 = cu[dy * 2 + 1].y;
          acc[o][0] += fabsf(a0 - w0) + fabsf(a1 - w1v) + fabsf(a2v - w2v);
          acc[o][1] += fabsf(a1 - w0) + fabsf(a2v - w1v) + fabsf(a3 - w2v);
        }
      }
    }
    // store + per-wave stats partials
#pragma unroll
    for (int o = 0; o < 8; o++) {
      float v0 = -acc[o][0], v1 = -acc[o][1];
      *(float2*)(a2b + (ogb + o) * HW) = make_float2(v0, v1);
      float s = v0 + v1, q = v0 * v0 + v1 * v1;
      for (int off = 32; off; off >>= 1) {
        s += __shfl_down(s, off, 64);
        q += __shfl_down(q, off, 64);
      }
      if (lane == 0) {
        red[wid * 32 + p * 16 + o * 2] = s;
        red[wid * 32 + p * 16 + o * 2 + 1] = q;
      }
    }
  }
  __syncthreads();
  if (tid < 32) {
    int oc = tid;
    int og = oc >> 3, o = oc & 7;
    int pp = og & 1, wb = (og >> 1) * 2;  // wave pair owning this og
    float s = red[wb * 32 + pp * 16 + o * 2] + red[(wb + 1) * 32 + pp * 16 + o * 2];
    float q = red[wb * 32 + pp * 16 + o * 2 + 1] + red[(wb + 1) * 32 + pp * 16 + o * 2 + 1];
    atomicAdd(&s2[oc], (double)s);
    atomicAdd(&s2[32 + oc], (double)q);
  }
}

// ---------------- Kernel 3: BN2 (inline params) + ReLU + avgpool + FC -------
__global__ __launch_bounds__(1024) void k_poolfc(const float* __restrict__ a2,
                                                 const double* __restrict__ s2,
                                                 const float* __restrict__ g2,
                                                 const float* __restrict__ b2,
                                                 const float* __restrict__ fw,
                                                 const float* __restrict__ fb,
                                                 float* __restrict__ out) {
  __shared__ float sc2s[32], sf2s[32];
  __shared__ float poolv[32];
  int b = blockIdx.x, tid = threadIdx.x;
  if (tid < 32) {  // inline BN2 params (block-redundant)
    double N = 1048576.0;
    double mean = s2[tid] / N;
    double var = s2[32 + tid] / N - mean * mean;
    float inv = (float)(1.0 / sqrt(var + 1e-5));
    float sc = g2[tid] * inv;
    sc2s[tid] = sc;
    sf2s[tid] = b2[tid] - (float)mean * sc;
  }
  __syncthreads();
  int o = tid >> 5, part = tid & 31;  // 32 threads per channel
  const float4* p = (const float4*)(a2 + ((size_t)b * 32 + o) * HW);
  float s = sc2s[o], f = sf2s[o];
  float acc = 0.f;
#pragma unroll
  for (int i = 0; i < 32; i++) {  // 32 iters * 32 threads * 4 = 4096
    float4 v = p[i * 32 + part];
    acc += fmaxf(fmaf(v.x, s, f), 0.f) + fmaxf(fmaf(v.y, s, f), 0.f) +
           fmaxf(fmaf(v.z, s, f), 0.f) + fmaxf(fmaf(v.w, s, f), 0.f);
  }
  acc += __shfl_down(acc, 16, 32);
  acc += __shfl_down(acc, 8, 32);
  acc += __shfl_down(acc, 4, 32);
  acc += __shfl_down(acc, 2, 32);
  acc += __shfl_down(acc, 1, 32);
  if (part == 0) poolv[o] = acc * (1.f / 4096.f);
  __syncthreads();
  if (tid < 10) {
    float rr = fb[tid];
#pragma unroll
    for (int oc = 0; oc < 32; oc++) rr += poolv[oc] * fw[tid * 32 + oc];
    out[b * 10 + tid] = rr;
  }
}

extern "C" void kernel_launch(void* const* d_in, const int* in_sizes, int n_in,
                              void* d_out, int out_size, void* d_ws, size_t ws_size,
                              hipStream_t stream) {
  const float* x   = (const float*)d_in[0];
  const float* w1  = (const float*)d_in[1];
  const float* g1  = (const float*)d_in[2];
  const float* b1  = (const float*)d_in[3];
  const float* w2  = (const float*)d_in[4];
  const float* g2  = (const float*)d_in[5];
  const float* b2  = (const float*)d_in[6];
  const float* fcw = (const float*)d_in[7];
  const float* fcb = (const float*)d_in[8];
  float* out = (float*)d_out;

  char* ws = (char*)d_ws;
  float* a2 = (float*)ws;                                  // 134,217,728 B
  double* stats = (double*)(ws + 134217728);               // 96 doubles
  double* s1 = stats;                                      // sum[16], sq[16]
  double* s2 = stats + 32;                                 // sum[32], sq[32]

  hipMemsetAsync(stats, 0, 768, stream);
  k_stats1<<<256, 256, 0, stream>>>(x, w1, s1);
  k_layer2<<<4096, 256, 0, stream>>>(x, w1, s1, g1, b1, w2, a2, s2);
  k_poolfc<<<256, 1024, 0, stream>>>(a2, s2, g2, b2, fcw, fcb, out);
}